// Round 6
// baseline (6407.540 us; speedup 1.0000x reference)
//
#include <hip/hip_runtime.h>
#include <hip/hip_bf16.h>

// ---------------------------------------------------------------------------
// KiperwasserDependencyParser: embed -> bi-LSTM x2 -> pairwise MLP -> softmax
// Round 6: 256-thr scan blocks (1 wave/SIMD -> 512 VGPR budget), 1 thread per
// gate row (256 weight f32 in regs), tagged 8-byte h messages (flag+data in
// one atomic load/store), depth-2 parity slots, 2 barriers/step, no fences.
// ---------------------------------------------------------------------------

#define L2E 1.4426950408889634f

__device__ __forceinline__ float fast_rcp(float x) { return __builtin_amdgcn_rcpf(x); }
__device__ __forceinline__ float sigm_f(float x) {
    return fast_rcp(1.f + exp2f(-x * L2E));
}
__device__ __forceinline__ float tanh_f(float x) {
    return 1.f - 2.f * fast_rcp(1.f + exp2f(x * (2.f * L2E)));
}

// ----------------------------- embed ---------------------------------------
__global__ __launch_bounds__(256) void embed_kernel(
    const float* __restrict__ wt, const float* __restrict__ pt,
    const int* __restrict__ wi, const int* __restrict__ pi,
    float* __restrict__ x)
{
    int idx = blockIdx.x * 256 + threadIdx.x;
    if (idx >= 1024 * 576) return;
    int n = idx / 576, c = idx % 576;
    x[idx] = (c < 512) ? wt[wi[n] * 512 + c] : pt[pi[n] * 64 + (c - 512)];
}

// --------------------------- GEMM + bias ------------------------------------
__global__ __launch_bounds__(256) void gemm_bias(
    const float* __restrict__ A,
    const float* __restrict__ W0, const float* __restrict__ W1,
    const float* __restrict__ b0, const float* __restrict__ b1,
    float* __restrict__ C0, float* __restrict__ C1,
    int M, int N, int K)
{
    const float* W = blockIdx.z ? W1 : W0;
    const float* bias = blockIdx.z ? b1 : b0;
    float* C = blockIdx.z ? C1 : C0;
    int m0 = blockIdx.y * 64, n0 = blockIdx.x * 64;
    __shared__ float As[16][65];
    __shared__ float Ws[16][65];
    int tid = threadIdx.x;
    int tx = tid & 15, ty = tid >> 4;
    float acc[4][4] = {};
    int lr = tid >> 2, lkc = (tid & 3) * 4;
    for (int k0 = 0; k0 < K; k0 += 16) {
        float4 a4 = *(const float4*)&A[(size_t)(m0 + lr) * K + k0 + lkc];
        float4 w4 = *(const float4*)&W[(size_t)(n0 + lr) * K + k0 + lkc];
        As[lkc + 0][lr] = a4.x; As[lkc + 1][lr] = a4.y;
        As[lkc + 2][lr] = a4.z; As[lkc + 3][lr] = a4.w;
        Ws[lkc + 0][lr] = w4.x; Ws[lkc + 1][lr] = w4.y;
        Ws[lkc + 2][lr] = w4.z; Ws[lkc + 3][lr] = w4.w;
        __syncthreads();
#pragma unroll
        for (int k = 0; k < 16; k++) {
            float a[4], b[4];
#pragma unroll
            for (int i = 0; i < 4; i++) a[i] = As[k][ty * 4 + i];
#pragma unroll
            for (int j = 0; j < 4; j++) b[j] = Ws[k][tx * 4 + j];
#pragma unroll
            for (int i = 0; i < 4; i++)
#pragma unroll
                for (int j = 0; j < 4; j++) acc[i][j] += a[i] * b[j];
        }
        __syncthreads();
    }
    int colbase = n0 + tx * 4;
    float4 bv = *(const float4*)&bias[colbase];
#pragma unroll
    for (int i = 0; i < 4; i++) {
        float4 o;
        o.x = acc[i][0] + bv.x; o.y = acc[i][1] + bv.y;
        o.z = acc[i][2] + bv.z; o.w = acc[i][3] + bv.w;
        *(float4*)&C[(size_t)(m0 + ty * 4 + i) * N + colbase] = o;
    }
}

// ----------------------------- LSTM scan ------------------------------------
// 8 blocks: dir = bid>>2, sub = bid&3. 256 threads (4 waves, 1/SIMD).
// Thread tid owns gate row R = gi*256 + sub*64 + lane (gi = wave = tid>>6);
// its 256 Whh weights live in registers (64 float4, scalar-pinned).
// Exchange: tagged 8-byte messages {tag=t+1, h} per (consumer, producer, lane)
// with depth-2 parity; one atomic store publishes, one atomic load both
// detects readiness and delivers the value. Race-free by lockstep argument:
// slot for t+1 last held tag t-1, which the consumer provably consumed before
// this producer could reach step t.
__global__ __launch_bounds__(256, 1) void lstm_scan(
    const float* __restrict__ xw_f, const float* __restrict__ xw_b,
    const float* __restrict__ Whh_f, const float* __restrict__ Whh_b,
    float* __restrict__ hout,                  // [1024][512]
    unsigned long long* __restrict__ hx)       // [2][4][4][2][64] tagged slots
{
    const int bid = blockIdx.x;
    const int dir = bid >> 2, sub = bid & 3;
    const float* __restrict__ xw  = dir ? xw_b : xw_f;
    const float* __restrict__ Whh = dir ? Whh_b : Whh_f;

    const int tid  = threadIdx.x;
    const int lane = tid & 63;
    const int wv   = tid >> 6;          // wave 0..3 == gate index
    const int gi   = wv;
    const int R    = gi * 256 + sub * 64 + lane;

    // ---- full weight row into registers: 256 f32 = 64 float4 ----
    float4 w4[64];
    {
        const float4* Wr = (const float4*)(Whh + (size_t)R * 256);
#pragma unroll
        for (int i = 0; i < 64; i++) w4[i] = Wr[i];
    }

    __shared__ float h_sh[256];
    __shared__ float gact[256];
    h_sh[tid] = 0.f;                    // h_0 = 0
    float c = 0.f;
    float xwv = xw[(size_t)(dir ? 1023 : 0) * 1024 + R];
    __syncthreads();

    for (int t = 0; t < 1024; t++) {
        // ---- stage 1: full 256-wide dot (LDS broadcast h), activation ----
        float a0 = 0.f, a1 = 0.f, a2 = 0.f, a3 = 0.f,
              a4 = 0.f, a5 = 0.f, a6 = 0.f, a7 = 0.f;
        const float4* hp4 = (const float4*)h_sh;   // wave-uniform broadcast
#pragma unroll
        for (int i = 0; i < 64; i += 8) {
            float4 h0v = hp4[i+0], h1v = hp4[i+1], h2v = hp4[i+2], h3v = hp4[i+3];
            float4 h4v = hp4[i+4], h5v = hp4[i+5], h6v = hp4[i+6], h7v = hp4[i+7];
            a0 += w4[i+0].x*h0v.x + w4[i+0].y*h0v.y + w4[i+0].z*h0v.z + w4[i+0].w*h0v.w;
            a1 += w4[i+1].x*h1v.x + w4[i+1].y*h1v.y + w4[i+1].z*h1v.z + w4[i+1].w*h1v.w;
            a2 += w4[i+2].x*h2v.x + w4[i+2].y*h2v.y + w4[i+2].z*h2v.z + w4[i+2].w*h2v.w;
            a3 += w4[i+3].x*h3v.x + w4[i+3].y*h3v.y + w4[i+3].z*h3v.z + w4[i+3].w*h3v.w;
            a4 += w4[i+4].x*h4v.x + w4[i+4].y*h4v.y + w4[i+4].z*h4v.z + w4[i+4].w*h4v.w;
            a5 += w4[i+5].x*h5v.x + w4[i+5].y*h5v.y + w4[i+5].z*h5v.z + w4[i+5].w*h5v.w;
            a6 += w4[i+6].x*h6v.x + w4[i+6].y*h6v.y + w4[i+6].z*h6v.z + w4[i+6].w*h6v.w;
            a7 += w4[i+7].x*h7v.x + w4[i+7].y*h7v.y + w4[i+7].z*h7v.z + w4[i+7].w*h7v.w;
        }
        float s = (((a0 + a1) + (a2 + a3)) + ((a4 + a5) + (a6 + a7))) + xwv;
        gact[tid] = (gi == 2) ? tanh_f(s) : sigm_f(s);
        if (t + 1 < 1024) {
            int trown = dir ? (1022 - t) : (t + 1);
            xwv = xw[(size_t)trown * 1024 + R];     // prefetch next step's row
        }
        __syncthreads();                             // b1

        // ---- stage 2: c/h update + publish (wave sub) | poll (others) ----
        if (wv == sub) {
            float iv = gact[lane], fv = gact[64 + lane],
                  gv = gact[128 + lane], ov = gact[192 + lane];
            c = fv * c + iv * gv;
            float h = ov * tanh_f(c);
            h_sh[sub * 64 + lane] = h;               // own chunk via LDS
            int trow = dir ? (1023 - t) : t;
            hout[(size_t)trow * 512 + dir * 256 + sub * 64 + lane] = h;
            if (t + 1 < 1024) {
                unsigned long long msg =
                    ((unsigned long long)(unsigned)(t + 1) << 32) |
                    (unsigned long long)__float_as_uint(h);
                int par = (t + 1) & 1;
#pragma unroll
                for (int cc = 0; cc < 4; cc++) {
                    if (cc == sub) continue;
                    __hip_atomic_store(
                        &hx[((((dir * 4 + cc) * 4 + sub) * 2 + par) << 6) + lane],
                        msg, __ATOMIC_RELAXED, __HIP_MEMORY_SCOPE_AGENT);
                }
            }
        } else if (t + 1 < 1024) {
            const unsigned long long* sp =
                &hx[((((dir * 4 + sub) * 4 + wv) * 2 + ((t + 1) & 1)) << 6) + lane];
            const unsigned want = (unsigned)(t + 1);
            unsigned long long v;
            do {
                v = __hip_atomic_load(sp, __ATOMIC_RELAXED, __HIP_MEMORY_SCOPE_AGENT);
            } while (!__all((unsigned)(v >> 32) == want));
            h_sh[wv * 64 + lane] = __uint_as_float((unsigned)v);
        }
        __syncthreads();                             // b2

        // pin weights live in VGPRs through the loop (0 instructions)
#pragma unroll
        for (int i = 0; i < 64; i++)
            asm volatile("" : "+v"(w4[i].x), "+v"(w4[i].y),
                              "+v"(w4[i].z), "+v"(w4[i].w));
    }
}

// ------------------------- transpose mlp_W1 ---------------------------------
__global__ __launch_bounds__(256) void transpose_w1(
    const float* __restrict__ W1, float* __restrict__ W1T)
{
    int idx = blockIdx.x * 256 + threadIdx.x;
    if (idx >= 100 * 1024) return;
    int n = idx / 1024, j = idx % 1024;
    W1T[j * 100 + n] = W1[idx];
}

// ---------------------- A = h1 Wh^T + b1, B = h1 Wm^T -----------------------
__global__ __launch_bounds__(256) void ab_kernel(
    const float* __restrict__ h1, const float* __restrict__ W1T,
    const float* __restrict__ b1v,
    float* __restrict__ Ab, float* __restrict__ Bb)
{
    int m0 = blockIdx.x * 16;
    __shared__ float hs[16][512];
    int tid = threadIdx.x;
    for (int idx = tid * 4; idx < 16 * 512; idx += 1024) {
        int r = idx >> 9, cc = idx & 511;
        *(float4*)&hs[r][cc] = *(const float4*)&h1[(size_t)(m0 + r) * 512 + cc];
    }
    __syncthreads();
    bool isB = tid >= 128;
    int n = tid & 127;
    if (n < 100) {
        float acc[16] = {};
        const float* wbase = W1T + (isB ? 512 * 100 : 0) + n;
#pragma unroll 4
        for (int k = 0; k < 512; k++) {
            float wv = wbase[k * 100];
#pragma unroll
            for (int m = 0; m < 16; m++) acc[m] += hs[m][k] * wv;
        }
        float badd = isB ? 0.f : b1v[n];
        float* dst = isB ? Bb : Ab;
#pragma unroll
        for (int m = 0; m < 16; m++) dst[(m0 + m) * 100 + n] = acc[m] + badd;
    }
}

// ------------------------------ pair MLP ------------------------------------
__global__ __launch_bounds__(256) void pair_kernel(
    const float* __restrict__ Ab, const float* __restrict__ Bb,
    const float* __restrict__ W2, const float* __restrict__ b2,
    float* __restrict__ sT)
{
    int i0 = blockIdx.x * 32, j0 = blockIdx.y * 32;
    __shared__ float Ash[32][101];
    __shared__ float Bsh[32][101];
    __shared__ float w2s[100];
    int tid = threadIdx.x;
    for (int idx = tid; idx < 3200; idx += 256) {
        int r = idx / 100, cc = idx % 100;
        Ash[r][cc] = Ab[(i0 + r) * 100 + cc];
        Bsh[r][cc] = Bb[(j0 + r) * 100 + cc];
    }
    if (tid < 100) w2s[tid] = W2[tid];
    __syncthreads();
    float b2v = b2[0];
    int il = (tid & 15) * 2, jl = (tid >> 4) * 2;
    float a00 = 0.f, a01 = 0.f, a10 = 0.f, a11 = 0.f;
#pragma unroll 4
    for (int k = 0; k < 100; k++) {
        float wv = w2s[k];
        float x0 = Ash[il][k], x1 = Ash[il + 1][k];
        float y0 = Bsh[jl][k], y1 = Bsh[jl + 1][k];
        a00 += wv * tanh_f(x0 + y0);
        a01 += wv * tanh_f(x0 + y1);
        a10 += wv * tanh_f(x1 + y0);
        a11 += wv * tanh_f(x1 + y1);
    }
    float vals[2][2] = {{a00, a01}, {a10, a11}};
#pragma unroll
    for (int a = 0; a < 2; a++)
#pragma unroll
        for (int b = 0; b < 2; b++) {
            int gi2 = i0 + il + a, gj = j0 + jl + b;
            float v = vals[a][b] + b2v;
            if (gi2 == gj) v = 0.f;
            sT[(size_t)gj * 1024 + gi2] = v;
        }
}

// ------------------------- column stats (softmax) ---------------------------
__global__ __launch_bounds__(256) void colstats(
    const float* __restrict__ sT, float* __restrict__ mx, float* __restrict__ rs)
{
    int j = blockIdx.x;
    const float* row = sT + (size_t)j * 1024;
    int tid = threadIdx.x;
    __shared__ float red[256];
    float m = -INFINITY;
    for (int i = tid; i < 1024; i += 256) m = fmaxf(m, row[i]);
    red[tid] = m; __syncthreads();
    for (int s = 128; s > 0; s >>= 1) {
        if (tid < s) red[tid] = fmaxf(red[tid], red[tid + s]);
        __syncthreads();
    }
    float mxv = red[0];
    __syncthreads();
    float ssum = 0.f;
    for (int i = tid; i < 1024; i += 256) ssum += exp2f((row[i] - mxv) * L2E);
    red[tid] = ssum; __syncthreads();
    for (int s = 128; s > 0; s >>= 1) {
        if (tid < s) red[tid] += red[tid + s];
        __syncthreads();
    }
    if (tid == 0) { mx[j] = mxv; rs[j] = 1.f / red[0]; }
}

// ----------------------- normalize + transpose write ------------------------
__global__ __launch_bounds__(256) void writeout(
    const float* __restrict__ sT, const float* __restrict__ mx,
    const float* __restrict__ rs, float* __restrict__ out)
{
    int i0 = blockIdx.x * 32, j0 = blockIdx.y * 32;
    __shared__ float til[32][33];
    int tid = threadIdx.x;
    int r = tid >> 3, c4 = (tid & 7) * 4;
    float4 v = *(const float4*)&sT[(size_t)(j0 + r) * 1024 + i0 + c4];
    til[r][c4 + 0] = v.x; til[r][c4 + 1] = v.y;
    til[r][c4 + 2] = v.z; til[r][c4 + 3] = v.w;
    __syncthreads();
    float4 o;
    float* op = &out[(size_t)(i0 + r) * 1024 + j0 + c4];
    o.x = exp2f((til[c4 + 0][r] - mx[j0 + c4 + 0]) * L2E) * rs[j0 + c4 + 0];
    o.y = exp2f((til[c4 + 1][r] - mx[j0 + c4 + 1]) * L2E) * rs[j0 + c4 + 1];
    o.z = exp2f((til[c4 + 2][r] - mx[j0 + c4 + 2]) * L2E) * rs[j0 + c4 + 2];
    o.w = exp2f((til[c4 + 3][r] - mx[j0 + c4 + 3]) * L2E) * rs[j0 + c4 + 3];
    *(float4*)op = o;
}

// ---------------------------------------------------------------------------
extern "C" void kernel_launch(void* const* d_in, const int* in_sizes, int n_in,
                              void* d_out, int out_size, void* d_ws, size_t ws_size,
                              hipStream_t stream)
{
    const float* word_table = (const float*)d_in[0];
    const float* pos_table  = (const float*)d_in[1];
    const float* l0f_Wih = (const float*)d_in[2];
    const float* l0f_Whh = (const float*)d_in[3];
    const float* l0f_b   = (const float*)d_in[4];
    const float* l0b_Wih = (const float*)d_in[5];
    const float* l0b_Whh = (const float*)d_in[6];
    const float* l0b_b   = (const float*)d_in[7];
    const float* l1f_Wih = (const float*)d_in[8];
    const float* l1f_Whh = (const float*)d_in[9];
    const float* l1f_b   = (const float*)d_in[10];
    const float* l1b_Wih = (const float*)d_in[11];
    const float* l1b_Whh = (const float*)d_in[12];
    const float* l1b_b   = (const float*)d_in[13];
    const float* mlp_W1  = (const float*)d_in[14];
    const float* mlp_b1  = (const float*)d_in[15];
    const float* mlp_W2  = (const float*)d_in[16];
    const float* mlp_b2  = (const float*)d_in[17];
    const int*   word_idx = (const int*)d_in[18];
    const int*   pos_idx  = (const int*)d_in[19];
    float* out = (float*)d_out;

    float* ws = (float*)d_ws;
    const size_t OFF_X   = 0;            // 1024*576
    const size_t OFF_XWF = 589824;       // 1024*1024
    const size_t OFF_XWB = 1638400;      // 1024*1024
    const size_t OFF_H0  = 2686976;      // 1024*512
    const size_t OFF_H1  = 3211264;      // 1024*512
    const size_t OFF_W1T = 3735552;      // 1024*100
    const size_t OFF_A   = 3837952;      // 1024*100
    const size_t OFF_B   = 3940352;      // 1024*100
    const size_t OFF_ST  = 4042752;      // 1024*1024
    const size_t OFF_MX  = 5091328;      // 1024
    const size_t OFF_RS  = 5092352;      // 1024
    const size_t OFF_HX  = 5095424;      // 2 scans * 4096 u64 (= 16384 floats)

    float* x   = ws + OFF_X;
    float* xwf = ws + OFF_XWF;
    float* xwb = ws + OFF_XWB;
    float* h0  = ws + OFF_H0;
    float* h1  = ws + OFF_H1;
    float* w1t = ws + OFF_W1T;
    float* Ab  = ws + OFF_A;
    float* Bb  = ws + OFF_B;
    float* sT  = ws + OFF_ST;
    float* mx  = ws + OFF_MX;
    float* rs  = ws + OFF_RS;
    unsigned long long* hx0 = (unsigned long long*)(ws + OFF_HX);
    unsigned long long* hx1 = hx0 + 4096;

    embed_kernel<<<(1024 * 576 + 255) / 256, 256, 0, stream>>>(
        word_table, pos_table, word_idx, pos_idx, x);

    transpose_w1<<<(100 * 1024 + 255) / 256, 256, 0, stream>>>(mlp_W1, w1t);

    gemm_bias<<<dim3(16, 16, 2), 256, 0, stream>>>(
        x, l0f_Wih, l0b_Wih, l0f_b, l0b_b, xwf, xwb, 1024, 1024, 576);

    lstm_scan<<<8, 256, 0, stream>>>(
        xwf, xwb, l0f_Whh, l0b_Whh, h0, hx0);

    gemm_bias<<<dim3(16, 16, 2), 256, 0, stream>>>(
        h0, l1f_Wih, l1b_Wih, l1f_b, l1b_b, xwf, xwb, 1024, 1024, 512);

    lstm_scan<<<8, 256, 0, stream>>>(
        xwf, xwb, l1f_Whh, l1b_Whh, h1, hx1);

    ab_kernel<<<64, 256, 0, stream>>>(h1, w1t, mlp_b1, Ab, Bb);

    pair_kernel<<<dim3(32, 32), 256, 0, stream>>>(Ab, Bb, mlp_W2, mlp_b2, sT);

    colstats<<<1024, 256, 0, stream>>>(sT, mx, rs);

    writeout<<<dim3(32, 32), 256, 0, stream>>>(sT, mx, rs, out);
}

// Round 7
// 5053.107 us; speedup vs baseline: 1.2680x; 1.2680x over previous
//
#include <hip/hip_runtime.h>
#include <hip/hip_bf16.h>

// ---------------------------------------------------------------------------
// KiperwasserDependencyParser: embed -> bi-LSTM x2 -> pairwise MLP -> softmax
// Round 7: scan with deterministic on-chip weights (64 f32/thread in regs +
// 64 f32/thread in transposed conflict-free LDS), 512 thr (2 waves/SIMD),
// tagged single-RT h handoff, 2 barriers/step.
// ---------------------------------------------------------------------------

#define L2E 1.4426950408889634f

__device__ __forceinline__ float fast_rcp(float x) { return __builtin_amdgcn_rcpf(x); }
__device__ __forceinline__ float sigm_f(float x) {
    return fast_rcp(1.f + exp2f(-x * L2E));
}
__device__ __forceinline__ float tanh_f(float x) {
    return 1.f - 2.f * fast_rcp(1.f + exp2f(x * (2.f * L2E)));
}

// ----------------------------- embed ---------------------------------------
__global__ __launch_bounds__(256) void embed_kernel(
    const float* __restrict__ wt, const float* __restrict__ pt,
    const int* __restrict__ wi, const int* __restrict__ pi,
    float* __restrict__ x)
{
    int idx = blockIdx.x * 256 + threadIdx.x;
    if (idx >= 1024 * 576) return;
    int n = idx / 576, c = idx % 576;
    x[idx] = (c < 512) ? wt[wi[n] * 512 + c] : pt[pi[n] * 64 + (c - 512)];
}

// --------------------------- GEMM + bias ------------------------------------
__global__ __launch_bounds__(256) void gemm_bias(
    const float* __restrict__ A,
    const float* __restrict__ W0, const float* __restrict__ W1,
    const float* __restrict__ b0, const float* __restrict__ b1,
    float* __restrict__ C0, float* __restrict__ C1,
    int M, int N, int K)
{
    const float* W = blockIdx.z ? W1 : W0;
    const float* bias = blockIdx.z ? b1 : b0;
    float* C = blockIdx.z ? C1 : C0;
    int m0 = blockIdx.y * 64, n0 = blockIdx.x * 64;
    __shared__ float As[16][65];
    __shared__ float Ws[16][65];
    int tid = threadIdx.x;
    int tx = tid & 15, ty = tid >> 4;
    float acc[4][4] = {};
    int lr = tid >> 2, lkc = (tid & 3) * 4;
    for (int k0 = 0; k0 < K; k0 += 16) {
        float4 a4 = *(const float4*)&A[(size_t)(m0 + lr) * K + k0 + lkc];
        float4 w4 = *(const float4*)&W[(size_t)(n0 + lr) * K + k0 + lkc];
        As[lkc + 0][lr] = a4.x; As[lkc + 1][lr] = a4.y;
        As[lkc + 2][lr] = a4.z; As[lkc + 3][lr] = a4.w;
        Ws[lkc + 0][lr] = w4.x; Ws[lkc + 1][lr] = w4.y;
        Ws[lkc + 2][lr] = w4.z; Ws[lkc + 3][lr] = w4.w;
        __syncthreads();
#pragma unroll
        for (int k = 0; k < 16; k++) {
            float a[4], b[4];
#pragma unroll
            for (int i = 0; i < 4; i++) a[i] = As[k][ty * 4 + i];
#pragma unroll
            for (int j = 0; j < 4; j++) b[j] = Ws[k][tx * 4 + j];
#pragma unroll
            for (int i = 0; i < 4; i++)
#pragma unroll
                for (int j = 0; j < 4; j++) acc[i][j] += a[i] * b[j];
        }
        __syncthreads();
    }
    int colbase = n0 + tx * 4;
    float4 bv = *(const float4*)&bias[colbase];
#pragma unroll
    for (int i = 0; i < 4; i++) {
        float4 o;
        o.x = acc[i][0] + bv.x; o.y = acc[i][1] + bv.y;
        o.z = acc[i][2] + bv.z; o.w = acc[i][3] + bv.w;
        *(float4*)&C[(size_t)(m0 + ty * 4 + i) * N + colbase] = o;
    }
}

// ----------------------------- LSTM scan ------------------------------------
// 8 blocks: dir = bid>>2, sub = bid&3. 512 threads (8 waves, 2/SIMD).
// Block `sub` owns h[64*sub..64*sub+64): 256 gate rows x 2 k-halves.
// Thread (row lr, half) -> weights k in [128*half,128*half+128):
//   first 64 in registers (scalar-pinned), last 64 in LDS transposed
//   wlds[half][kk][lr] (lanes read consecutive rows -> 2/bank, conflict-free).
// Handoff: tagged {tag=t+1, h} 8B relaxed-agent messages, depth-2 parity;
// one store publishes, one load detects+delivers. Consumers: waves 1..3,
// wave w polls producer (sub+w)&3. 2 barriers/step, no fences.
__global__ __launch_bounds__(512, 2) void lstm_scan(
    const float* __restrict__ xw_f, const float* __restrict__ xw_b,
    const float* __restrict__ Whh_f, const float* __restrict__ Whh_b,
    float* __restrict__ hout,                  // [1024][512]
    unsigned long long* __restrict__ hx)       // [2][4][4][2][64] tagged slots
{
    const int bid = blockIdx.x;
    const int dir = bid >> 2, sub = bid & 3;
    const float* __restrict__ xw  = dir ? xw_b : xw_f;
    const float* __restrict__ Whh = dir ? Whh_b : Whh_f;

    const int tid  = threadIdx.x;
    const int lane = tid & 63;
    const int wv   = tid >> 6;         // wave 0..7
    const int half = tid >> 8;         // k-half 0/1 (wave-uniform)
    const int lr   = tid & 255;        // local gate row 0..255
    const int gi   = lr >> 6;          // 0=i 1=f 2=g 3=o
    const int R    = gi * 256 + sub * 64 + (lr & 63);   // global gate row

    __shared__ float wlds[2][64][256]; // transposed weight store (128 KB)
    __shared__ float h_sh[256];
    __shared__ float part[512];

    // ---- weights: k in [128h,128h+64) -> 16 float4 regs ----
    float4 wr[16];
    const float* Wrow = Whh + (size_t)R * 256 + (half << 7);
#pragma unroll
    for (int i = 0; i < 16; i++) wr[i] = ((const float4*)Wrow)[i];
    // ---- weights: k in [128h+64,128h+128) -> LDS transposed ----
#pragma unroll
    for (int kk = 0; kk < 64; kk++) wlds[half][kk][lr] = Wrow[64 + kk];

    if (tid < 256) h_sh[tid] = 0.f;    // h_0 = 0
    float c = 0.f;
    float xwv = (tid < 256) ? xw[(size_t)(dir ? 1023 : 0) * 1024 + R] : 0.f;
    __syncthreads();

    for (int t = 0; t < 1024; t++) {
        // ---- phase 1: dot over this thread's 128-k-slice ----
        float a0 = 0.f, a1 = 0.f, a2 = 0.f, a3 = 0.f;
        const float4* hp4 = (const float4*)&h_sh[half << 7];  // bcast reads
#pragma unroll
        for (int i = 0; i < 16; i += 4) {
            float4 h0 = hp4[i], h1 = hp4[i + 1], h2 = hp4[i + 2], h3 = hp4[i + 3];
            a0 += wr[i+0].x*h0.x + wr[i+0].y*h0.y + wr[i+0].z*h0.z + wr[i+0].w*h0.w;
            a1 += wr[i+1].x*h1.x + wr[i+1].y*h1.y + wr[i+1].z*h1.z + wr[i+1].w*h1.w;
            a2 += wr[i+2].x*h2.x + wr[i+2].y*h2.y + wr[i+2].z*h2.z + wr[i+2].w*h2.w;
            a3 += wr[i+3].x*h3.x + wr[i+3].y*h3.y + wr[i+3].z*h3.z + wr[i+3].w*h3.w;
        }
        const float* hb = &h_sh[(half << 7) + 64];            // bcast reads
#pragma unroll
        for (int kk = 0; kk < 64; kk += 4) {
            float h0 = hb[kk], h1 = hb[kk + 1], h2 = hb[kk + 2], h3 = hb[kk + 3];
            a0 += wlds[half][kk + 0][lr] * h0;
            a1 += wlds[half][kk + 1][lr] * h1;
            a2 += wlds[half][kk + 2][lr] * h2;
            a3 += wlds[half][kk + 3][lr] * h3;
        }
        part[tid] = ((a0 + a1) + (a2 + a3)) + (half ? 0.f : xwv);
        if (half == 0 && t + 1 < 1024) {
            int trown = dir ? (1022 - t) : (t + 1);
            xwv = xw[(size_t)trown * 1024 + R];   // prefetch, lands during sync
        }
        __syncthreads();                                      // b1

        // ---- phase 2: gates + c/h + publish (wave 0) | poll (waves 1-3) ----
        if (tid < 64) {
            float s0 = part[tid]       + part[256 + tid];
            float s1 = part[64 + tid]  + part[320 + tid];
            float s2 = part[128 + tid] + part[384 + tid];
            float s3 = part[192 + tid] + part[448 + tid];
            float iv = sigm_f(s0), fv = sigm_f(s1);
            float gv = tanh_f(s2), ov = sigm_f(s3);
            c = fv * c + iv * gv;
            float h = ov * tanh_f(c);
            h_sh[sub * 64 + lane] = h;            // own chunk via LDS
            int trow = dir ? (1023 - t) : t;
            hout[(size_t)trow * 512 + dir * 256 + sub * 64 + lane] = h;
            if (t + 1 < 1024) {
                unsigned long long msg =
                    ((unsigned long long)(unsigned)(t + 1) << 32) |
                    (unsigned long long)__float_as_uint(h);
                int par = (t + 1) & 1;
#pragma unroll
                for (int k = 1; k < 4; k++) {
                    int cc = (sub + k) & 3;
                    __hip_atomic_store(
                        &hx[((((dir * 4 + cc) * 4 + sub) * 2 + par) << 6) + lane],
                        msg, __ATOMIC_RELAXED, __HIP_MEMORY_SCOPE_AGENT);
                }
            }
        } else if (wv <= 3 && t + 1 < 1024) {
            int pw = (sub + wv) & 3;              // producer this wave tracks
            const unsigned long long* sp =
                &hx[((((dir * 4 + sub) * 4 + pw) * 2 + ((t + 1) & 1)) << 6) + lane];
            const unsigned want = (unsigned)(t + 1);
            unsigned long long v =
                __hip_atomic_load(sp, __ATOMIC_RELAXED, __HIP_MEMORY_SCOPE_AGENT);
            while ((unsigned)(v >> 32) != want)
                v = __hip_atomic_load(sp, __ATOMIC_RELAXED, __HIP_MEMORY_SCOPE_AGENT);
            h_sh[pw * 64 + lane] = __uint_as_float((unsigned)v);
        }
        __syncthreads();                                      // b2

        // keep register weights live (scalar ties; compiled OK in R5/R6)
#pragma unroll
        for (int i = 0; i < 16; i++)
            asm volatile("" : "+v"(wr[i].x), "+v"(wr[i].y),
                              "+v"(wr[i].z), "+v"(wr[i].w));
    }
}

// ------------------------- transpose mlp_W1 ---------------------------------
__global__ __launch_bounds__(256) void transpose_w1(
    const float* __restrict__ W1, float* __restrict__ W1T)
{
    int idx = blockIdx.x * 256 + threadIdx.x;
    if (idx >= 100 * 1024) return;
    int n = idx / 1024, j = idx % 1024;
    W1T[j * 100 + n] = W1[idx];
}

// ---------------------- A = h1 Wh^T + b1, B = h1 Wm^T -----------------------
__global__ __launch_bounds__(256) void ab_kernel(
    const float* __restrict__ h1, const float* __restrict__ W1T,
    const float* __restrict__ b1v,
    float* __restrict__ Ab, float* __restrict__ Bb)
{
    int m0 = blockIdx.x * 16;
    __shared__ float hs[16][512];
    int tid = threadIdx.x;
    for (int idx = tid * 4; idx < 16 * 512; idx += 1024) {
        int r = idx >> 9, cc = idx & 511;
        *(float4*)&hs[r][cc] = *(const float4*)&h1[(size_t)(m0 + r) * 512 + cc];
    }
    __syncthreads();
    bool isB = tid >= 128;
    int n = tid & 127;
    if (n < 100) {
        float acc[16] = {};
        const float* wbase = W1T + (isB ? 512 * 100 : 0) + n;
#pragma unroll 4
        for (int k = 0; k < 512; k++) {
            float wv = wbase[k * 100];
#pragma unroll
            for (int m = 0; m < 16; m++) acc[m] += hs[m][k] * wv;
        }
        float badd = isB ? 0.f : b1v[n];
        float* dst = isB ? Bb : Ab;
#pragma unroll
        for (int m = 0; m < 16; m++) dst[(m0 + m) * 100 + n] = acc[m] + badd;
    }
}

// ------------------------------ pair MLP ------------------------------------
__global__ __launch_bounds__(256) void pair_kernel(
    const float* __restrict__ Ab, const float* __restrict__ Bb,
    const float* __restrict__ W2, const float* __restrict__ b2,
    float* __restrict__ sT)
{
    int i0 = blockIdx.x * 32, j0 = blockIdx.y * 32;
    __shared__ float Ash[32][101];
    __shared__ float Bsh[32][101];
    __shared__ float w2s[100];
    int tid = threadIdx.x;
    for (int idx = tid; idx < 3200; idx += 256) {
        int r = idx / 100, cc = idx % 100;
        Ash[r][cc] = Ab[(i0 + r) * 100 + cc];
        Bsh[r][cc] = Bb[(j0 + r) * 100 + cc];
    }
    if (tid < 100) w2s[tid] = W2[tid];
    __syncthreads();
    float b2v = b2[0];
    int il = (tid & 15) * 2, jl = (tid >> 4) * 2;
    float a00 = 0.f, a01 = 0.f, a10 = 0.f, a11 = 0.f;
#pragma unroll 4
    for (int k = 0; k < 100; k++) {
        float wv = w2s[k];
        float x0 = Ash[il][k], x1 = Ash[il + 1][k];
        float y0 = Bsh[jl][k], y1 = Bsh[jl + 1][k];
        a00 += wv * tanh_f(x0 + y0);
        a01 += wv * tanh_f(x0 + y1);
        a10 += wv * tanh_f(x1 + y0);
        a11 += wv * tanh_f(x1 + y1);
    }
    float vals[2][2] = {{a00, a01}, {a10, a11}};
#pragma unroll
    for (int a = 0; a < 2; a++)
#pragma unroll
        for (int b = 0; b < 2; b++) {
            int gi2 = i0 + il + a, gj = j0 + jl + b;
            float v = vals[a][b] + b2v;
            if (gi2 == gj) v = 0.f;
            sT[(size_t)gj * 1024 + gi2] = v;
        }
}

// ------------------------- column stats (softmax) ---------------------------
__global__ __launch_bounds__(256) void colstats(
    const float* __restrict__ sT, float* __restrict__ mx, float* __restrict__ rs)
{
    int j = blockIdx.x;
    const float* row = sT + (size_t)j * 1024;
    int tid = threadIdx.x;
    __shared__ float red[256];
    float m = -INFINITY;
    for (int i = tid; i < 1024; i += 256) m = fmaxf(m, row[i]);
    red[tid] = m; __syncthreads();
    for (int s = 128; s > 0; s >>= 1) {
        if (tid < s) red[tid] = fmaxf(red[tid], red[tid + s]);
        __syncthreads();
    }
    float mxv = red[0];
    __syncthreads();
    float ssum = 0.f;
    for (int i = tid; i < 1024; i += 256) ssum += exp2f((row[i] - mxv) * L2E);
    red[tid] = ssum; __syncthreads();
    for (int s = 128; s > 0; s >>= 1) {
        if (tid < s) red[tid] += red[tid + s];
        __syncthreads();
    }
    if (tid == 0) { mx[j] = mxv; rs[j] = 1.f / red[0]; }
}

// ----------------------- normalize + transpose write ------------------------
__global__ __launch_bounds__(256) void writeout(
    const float* __restrict__ sT, const float* __restrict__ mx,
    const float* __restrict__ rs, float* __restrict__ out)
{
    int i0 = blockIdx.x * 32, j0 = blockIdx.y * 32;
    __shared__ float til[32][33];
    int tid = threadIdx.x;
    int r = tid >> 3, c4 = (tid & 7) * 4;
    float4 v = *(const float4*)&sT[(size_t)(j0 + r) * 1024 + i0 + c4];
    til[r][c4 + 0] = v.x; til[r][c4 + 1] = v.y;
    til[r][c4 + 2] = v.z; til[r][c4 + 3] = v.w;
    __syncthreads();
    float4 o;
    float* op = &out[(size_t)(i0 + r) * 1024 + j0 + c4];
    o.x = exp2f((til[c4 + 0][r] - mx[j0 + c4 + 0]) * L2E) * rs[j0 + c4 + 0];
    o.y = exp2f((til[c4 + 1][r] - mx[j0 + c4 + 1]) * L2E) * rs[j0 + c4 + 1];
    o.z = exp2f((til[c4 + 2][r] - mx[j0 + c4 + 2]) * L2E) * rs[j0 + c4 + 2];
    o.w = exp2f((til[c4 + 3][r] - mx[j0 + c4 + 3]) * L2E) * rs[j0 + c4 + 3];
    *(float4*)op = o;
}

// ---------------------------------------------------------------------------
extern "C" void kernel_launch(void* const* d_in, const int* in_sizes, int n_in,
                              void* d_out, int out_size, void* d_ws, size_t ws_size,
                              hipStream_t stream)
{
    const float* word_table = (const float*)d_in[0];
    const float* pos_table  = (const float*)d_in[1];
    const float* l0f_Wih = (const float*)d_in[2];
    const float* l0f_Whh = (const float*)d_in[3];
    const float* l0f_b   = (const float*)d_in[4];
    const float* l0b_Wih = (const float*)d_in[5];
    const float* l0b_Whh = (const float*)d_in[6];
    const float* l0b_b   = (const float*)d_in[7];
    const float* l1f_Wih = (const float*)d_in[8];
    const float* l1f_Whh = (const float*)d_in[9];
    const float* l1f_b   = (const float*)d_in[10];
    const float* l1b_Wih = (const float*)d_in[11];
    const float* l1b_Whh = (const float*)d_in[12];
    const float* l1b_b   = (const float*)d_in[13];
    const float* mlp_W1  = (const float*)d_in[14];
    const float* mlp_b1  = (const float*)d_in[15];
    const float* mlp_W2  = (const float*)d_in[16];
    const float* mlp_b2  = (const float*)d_in[17];
    const int*   word_idx = (const int*)d_in[18];
    const int*   pos_idx  = (const int*)d_in[19];
    float* out = (float*)d_out;

    float* ws = (float*)d_ws;
    const size_t OFF_X   = 0;            // 1024*576
    const size_t OFF_XWF = 589824;       // 1024*1024
    const size_t OFF_XWB = 1638400;      // 1024*1024
    const size_t OFF_H0  = 2686976;      // 1024*512
    const size_t OFF_H1  = 3211264;      // 1024*512
    const size_t OFF_W1T = 3735552;      // 1024*100
    const size_t OFF_A   = 3837952;      // 1024*100
    const size_t OFF_B   = 3940352;      // 1024*100
    const size_t OFF_ST  = 4042752;      // 1024*1024
    const size_t OFF_MX  = 5091328;      // 1024
    const size_t OFF_RS  = 5092352;      // 1024
    const size_t OFF_HX  = 5095424;      // 2 scans * 4096 u64 (16384 floats)

    float* x   = ws + OFF_X;
    float* xwf = ws + OFF_XWF;
    float* xwb = ws + OFF_XWB;
    float* h0  = ws + OFF_H0;
    float* h1  = ws + OFF_H1;
    float* w1t = ws + OFF_W1T;
    float* Ab  = ws + OFF_A;
    float* Bb  = ws + OFF_B;
    float* sT  = ws + OFF_ST;
    float* mx  = ws + OFF_MX;
    float* rs  = ws + OFF_RS;
    unsigned long long* hx0 = (unsigned long long*)(ws + OFF_HX);
    unsigned long long* hx1 = hx0 + 4096;

    // zero tagged slots so graph replays never consume stale tags
    hipMemsetAsync(hx0, 0, 8192 * sizeof(unsigned long long), stream);

    embed_kernel<<<(1024 * 576 + 255) / 256, 256, 0, stream>>>(
        word_table, pos_table, word_idx, pos_idx, x);

    transpose_w1<<<(100 * 1024 + 255) / 256, 256, 0, stream>>>(mlp_W1, w1t);

    gemm_bias<<<dim3(16, 16, 2), 256, 0, stream>>>(
        x, l0f_Wih, l0b_Wih, l0f_b, l0b_b, xwf, xwb, 1024, 1024, 576);

    lstm_scan<<<8, 512, 0, stream>>>(
        xwf, xwb, l0f_Whh, l0b_Whh, h0, hx0);

    gemm_bias<<<dim3(16, 16, 2), 256, 0, stream>>>(
        h0, l1f_Wih, l1b_Wih, l1f_b, l1b_b, xwf, xwb, 1024, 1024, 512);

    lstm_scan<<<8, 512, 0, stream>>>(
        xwf, xwb, l1f_Whh, l1b_Whh, h1, hx1);

    ab_kernel<<<64, 256, 0, stream>>>(h1, w1t, mlp_b1, Ab, Bb);

    pair_kernel<<<dim3(32, 32), 256, 0, stream>>>(Ab, Bb, mlp_W2, mlp_b2, sT);

    colstats<<<1024, 256, 0, stream>>>(sT, mx, rs);

    writeout<<<dim3(32, 32), 256, 0, stream>>>(sT, mx, rs, out);
}